// Round 1
// baseline (449.121 us; speedup 1.0000x reference)
//
#include <hip/hip_runtime.h>

#define BB 4
#define LL 2048
#define DD 1024
#define HH 16
#define HD 64

typedef __attribute__((ext_vector_type(8))) short s16x8;
typedef __attribute__((ext_vector_type(4))) short s16x4;
typedef __attribute__((ext_vector_type(4))) float f32x4;

__device__ __forceinline__ short f2bf(float f) {
  union { float f; unsigned u; } c;
  c.f = f;
  return (short)((c.u + 0x7fffu + ((c.u >> 16) & 1u)) >> 16);  // RNE
}

// ---------------- fp32 -> bf16 convert ----------------
__global__ __launch_bounds__(256) void f2b_kernel(const float* __restrict__ in,
                                                  short* __restrict__ out, int n4) {
  int i = blockIdx.x * blockDim.x + threadIdx.x;
  if (i >= n4) return;
  float4 v = ((const float4*)in)[i];
  s16x4 o;
  o[0] = f2bf(v.x);
  o[1] = f2bf(v.y);
  o[2] = f2bf(v.z);
  o[3] = f2bf(v.w);
  ((s16x4*)out)[i] = o;
}

// ---------------- GEMM: C[M,N] = A[M,K] * B[N,K]^T (bf16 in, MFMA) ----------
// MODE 0: scatter bf16 into Q/K/V [B,H,L,HD].  MODE 1: fp32 row-major out.
template <int MODE>
__global__ __launch_bounds__(256) void gemm_bt(const short* __restrict__ A,
                                               const short* __restrict__ Bm,
                                               int K, int N,
                                               short* __restrict__ qo,
                                               short* __restrict__ ko,
                                               short* __restrict__ vo,
                                               float* __restrict__ fo) {
  __shared__ __align__(16) short As[128 * 32];
  __shared__ __align__(16) short Bs[128 * 32];
  const int tid = threadIdx.x;
  const int m0 = blockIdx.y * 128, n0 = blockIdx.x * 128;
  const int wave = tid >> 6, lane = tid & 63;
  const int quad = lane >> 4, c16 = lane & 15;
  const int wr = (wave >> 1) * 64, wc = (wave & 1) * 64;

  f32x4 zero = {0.f, 0.f, 0.f, 0.f};
  f32x4 acc[4][4];
#pragma unroll
  for (int i = 0; i < 4; i++)
#pragma unroll
    for (int j = 0; j < 4; j++) acc[i][j] = zero;

  const int row1 = tid >> 2, seg1 = tid & 3;  // 64 rows x 4 16B-segments
  const int row2 = row1 + 64;

  for (int k0 = 0; k0 < K; k0 += 32) {
    uint4 a0 = *(const uint4*)(A + (size_t)(m0 + row1) * K + k0 + seg1 * 8);
    uint4 b0 = *(const uint4*)(Bm + (size_t)(n0 + row1) * K + k0 + seg1 * 8);
    uint4 a1 = *(const uint4*)(A + (size_t)(m0 + row2) * K + k0 + seg1 * 8);
    uint4 b1 = *(const uint4*)(Bm + (size_t)(n0 + row2) * K + k0 + seg1 * 8);
    __syncthreads();
    *(uint4*)&As[row1 * 32 + seg1 * 8] = a0;
    *(uint4*)&Bs[row1 * 32 + seg1 * 8] = b0;
    *(uint4*)&As[row2 * 32 + seg1 * 8] = a1;
    *(uint4*)&Bs[row2 * 32 + seg1 * 8] = b1;
    __syncthreads();
    s16x8 af[4], bf[4];
#pragma unroll
    for (int i = 0; i < 4; i++)
      af[i] = *(const s16x8*)&As[(wr + i * 16 + c16) * 32 + quad * 8];
#pragma unroll
    for (int j = 0; j < 4; j++)
      bf[j] = *(const s16x8*)&Bs[(wc + j * 16 + c16) * 32 + quad * 8];
#pragma unroll
    for (int i = 0; i < 4; i++)
#pragma unroll
      for (int j = 0; j < 4; j++)
        acc[i][j] = __builtin_amdgcn_mfma_f32_16x16x32_bf16(af[i], bf[j], acc[i][j], 0, 0, 0);
  }

  if (MODE == 0) {
#pragma unroll
    for (int j = 0; j < 4; j++) {
      const int gn = n0 + wc + j * 16 + c16;       // 0..3071
      const int which = gn >> 10;
      const int h = (gn >> 6) & 15;
      const int hd = gn & 63;
      short* dst = which == 0 ? qo : (which == 1 ? ko : vo);
#pragma unroll
      for (int i = 0; i < 4; i++)
#pragma unroll
        for (int r = 0; r < 4; r++) {
          const int gm = m0 + wr + i * 16 + quad * 4 + r;  // 0..8191
          const int b = gm >> 11, l = gm & 2047;
          dst[((size_t)((b << 4) + h) * LL + l) * HD + hd] = f2bf(acc[i][j][r]);
        }
    }
  } else {
#pragma unroll
    for (int i = 0; i < 4; i++)
#pragma unroll
      for (int r = 0; r < 4; r++) {
        const int gm = m0 + wr + i * 16 + quad * 4 + r;
#pragma unroll
        for (int j = 0; j < 4; j++) {
          const int gn = n0 + wc + j * 16 + c16;
          fo[(size_t)gm * N + gn] = acc[i][j][r];
        }
      }
  }
}

// ---------------- flash attention, causal, 1 wave per 16-query tile ---------
__global__ __launch_bounds__(64) void attn_kernel(const short* __restrict__ Qb,
                                                  const short* __restrict__ Kb,
                                                  const short* __restrict__ Vb,
                                                  short* __restrict__ Cb) {
  const int qt = blockIdx.x;   // 0..127
  const int bh = blockIdx.y;   // 0..63
  const int lane = threadIdx.x;
  const int quad = lane >> 4, c16 = lane & 15;
  const size_t base = (size_t)bh * LL * HD;
  const short* Q = Qb + base;
  const short* K = Kb + base;
  const short* V = Vb + base;
  const int q0 = qt * 16;
  const float NEG_INF = -__builtin_inff();

  s16x8 qf[2];
#pragma unroll
  for (int s = 0; s < 2; s++)
    qf[s] = *(const s16x8*)(Q + (q0 + c16) * HD + s * 32 + quad * 8);

  f32x4 zero = {0.f, 0.f, 0.f, 0.f};
  f32x4 o[4];
#pragma unroll
  for (int j = 0; j < 4; j++) o[j] = zero;
  float m_i[4], l_i[4];
#pragma unroll
  for (int r = 0; r < 4; r++) {
    m_i[r] = NEG_INF;
    l_i[r] = 0.f;
  }

  __shared__ __align__(16) short pbuf[16 * 32];

  const int kend = q0 + 16;
  for (int kb = 0; kb < kend; kb += 32) {
    f32x4 s0 = zero, s1 = zero;
#pragma unroll
    for (int s = 0; s < 2; s++) {
      s16x8 kf0 = *(const s16x8*)(K + (kb + c16) * HD + s * 32 + quad * 8);
      s16x8 kf1 = *(const s16x8*)(K + (kb + 16 + c16) * HD + s * 32 + quad * 8);
      s0 = __builtin_amdgcn_mfma_f32_16x16x32_bf16(qf[s], kf0, s0, 0, 0, 0);
      s1 = __builtin_amdgcn_mfma_f32_16x16x32_bf16(qf[s], kf1, s1, 0, 0, 0);
    }
#pragma unroll
    for (int r = 0; r < 4; r++) {
      const int qrow = q0 + quad * 4 + r;
      float v0 = s0[r] * 0.125f;  // 1/sqrt(64)
      float v1 = s1[r] * 0.125f;
      if (kb + c16 > qrow) v0 = NEG_INF;
      if (kb + 16 + c16 > qrow) v1 = NEG_INF;
      float m = fmaxf(v0, v1);
      m = fmaxf(m, __shfl_xor(m, 1));
      m = fmaxf(m, __shfl_xor(m, 2));
      m = fmaxf(m, __shfl_xor(m, 4));
      m = fmaxf(m, __shfl_xor(m, 8));
      const float mnew = fmaxf(m_i[r], m);
      const float alpha = __expf(m_i[r] - mnew);
      m_i[r] = mnew;
      const float p0 = __expf(v0 - mnew);
      const float p1 = __expf(v1 - mnew);
      pbuf[(quad * 4 + r) * 32 + c16] = f2bf(p0);
      pbuf[(quad * 4 + r) * 32 + 16 + c16] = f2bf(p1);
      float sum = p0 + p1;
      sum += __shfl_xor(sum, 1);
      sum += __shfl_xor(sum, 2);
      sum += __shfl_xor(sum, 4);
      sum += __shfl_xor(sum, 8);
      l_i[r] = l_i[r] * alpha + sum;
#pragma unroll
      for (int j = 0; j < 4; j++) o[j][r] *= alpha;
    }
    __syncthreads();  // pbuf writes -> reads (single-wave block)
    s16x8 pa = *(const s16x8*)(pbuf + c16 * 32 + quad * 8);
#pragma unroll
    for (int j4 = 0; j4 < 4; j4++) {
      s16x8 vf;
#pragma unroll
      for (int jj = 0; jj < 8; jj++)
        vf[jj] = V[(kb + quad * 8 + jj) * HD + j4 * 16 + c16];
      o[j4] = __builtin_amdgcn_mfma_f32_16x16x32_bf16(pa, vf, o[j4], 0, 0, 0);
    }
    __syncthreads();  // protect pbuf from next iter's writes
  }

  const int b = bh >> 4, h = bh & 15;
#pragma unroll
  for (int j4 = 0; j4 < 4; j4++)
#pragma unroll
    for (int r = 0; r < 4; r++) {
      const int qrow = q0 + quad * 4 + r;
      const float val = o[j4][r] / l_i[r];
      Cb[(size_t)(b * LL + qrow) * DD + h * HD + j4 * 16 + c16] = f2bf(val);
    }
}

// ---------------- launch ----------------
extern "C" void kernel_launch(void* const* d_in, const int* in_sizes, int n_in,
                              void* d_out, int out_size, void* d_ws, size_t ws_size,
                              hipStream_t stream) {
  const float* x = (const float*)d_in[0];
  const float* wqkv = (const float*)d_in[1];
  const float* wout = (const float*)d_in[2];
  float* out = (float*)d_out;

  const size_t NX = (size_t)BB * LL * DD;  // 8388608
  short* xb = (short*)d_ws;
  short* wqkvb = xb + NX;
  short* woutb = wqkvb + (size_t)3 * DD * DD;
  short* qb = woutb + (size_t)DD * DD;
  short* kb = qb + NX;
  short* vb = kb + NX;
  short* cb = vb + NX;
  // total: 92,274,688 bytes of d_ws

  f2b_kernel<<<dim3((unsigned)(NX / 4 / 256)), 256, 0, stream>>>(x, xb, (int)(NX / 4));
  f2b_kernel<<<dim3(3 * DD * DD / 4 / 256), 256, 0, stream>>>(wqkv, wqkvb, 3 * DD * DD / 4);
  f2b_kernel<<<dim3(DD * DD / 4 / 256), 256, 0, stream>>>(wout, woutb, DD * DD / 4);

  gemm_bt<0><<<dim3(3 * DD / 128, BB * LL / 128), 256, 0, stream>>>(
      xb, wqkvb, DD, 3 * DD, qb, kb, vb, nullptr);
  attn_kernel<<<dim3(LL / 16, BB * HH), 64, 0, stream>>>(qb, kb, vb, cb);
  gemm_bt<1><<<dim3(DD / 128, BB * LL / 128), 256, 0, stream>>>(
      cb, woutb, DD, DD, nullptr, nullptr, nullptr, out);
}